// Round 1
// baseline (6166.969 us; speedup 1.0000x reference)
//
#include <hip/hip_runtime.h>
#include <hip/hip_bf16.h>
#include <math.h>

// Problem constants
#define B_   2
#define S_   2048
#define D_   1024
#define H_   16
#define HD_  64
#define DFF_ 4096
#define M_   (B_*S_)   // 4096 rows

__device__ __forceinline__ float softplus_f(float x) {
    // stable log1p(exp(x))
    return fmaxf(x, 0.f) + log1pf(expf(-fabsf(x)));
}

// ---------------------------------------------------------------------------
// Generic fp32 GEMM: C[M,N] = A[M,K] @ W[K,N] + bias[N], optional relu.
// 64x64 C tile per block, 256 threads, each thread 4x4. LDS-tiled, TK=16.
// ---------------------------------------------------------------------------
__global__ __launch_bounds__(256) void gemm_bias_kernel(
    const float* __restrict__ A, const float* __restrict__ W,
    const float* __restrict__ bias, float* __restrict__ C,
    int M, int K, int N, int relu)
{
    __shared__ float As[16][65];   // [k][m], +1 pad to break bank conflicts on store
    __shared__ float Ws[16][64];   // [k][n]

    const int tid = threadIdx.x;
    const int tx  = tid & 15;      // 0..15 -> 4 cols each
    const int ty  = tid >> 4;      // 0..15 -> 4 rows each
    const int m0  = blockIdx.y * 64;
    const int n0  = blockIdx.x * 64;

    const int arow = tid >> 4;     // 0..15 (row group for A load)
    const int acol = tid & 15;     // k for A load
    const int wrow = tid >> 6;     // 0..3  (k group for W load)
    const int wcol = tid & 63;     // n for W load

    float acc[4][4] = {};

    for (int k0 = 0; k0 < K; k0 += 16) {
        #pragma unroll
        for (int i = 0; i < 4; i++) {
            As[acol][arow + 16*i] = A[(size_t)(m0 + arow + 16*i) * K + (k0 + acol)];
        }
        #pragma unroll
        for (int i = 0; i < 4; i++) {
            Ws[wrow + 4*i][wcol] = W[(size_t)(k0 + wrow + 4*i) * N + (n0 + wcol)];
        }
        __syncthreads();

        #pragma unroll
        for (int kk = 0; kk < 16; kk++) {
            float a[4];
            #pragma unroll
            for (int i = 0; i < 4; i++) a[i] = As[kk][ty*4 + i];
            float4 bv = *(const float4*)&Ws[kk][tx*4];
            float b4[4] = {bv.x, bv.y, bv.z, bv.w};
            #pragma unroll
            for (int i = 0; i < 4; i++)
                #pragma unroll
                for (int j = 0; j < 4; j++)
                    acc[i][j] += a[i] * b4[j];
        }
        __syncthreads();
    }

    float4 bb = *(const float4*)&bias[n0 + tx*4];
    float badd[4] = {bb.x, bb.y, bb.z, bb.w};
    #pragma unroll
    for (int i = 0; i < 4; i++) {
        int row = m0 + ty*4 + i;
        float4 o;
        float* op = (float*)&o;
        #pragma unroll
        for (int j = 0; j < 4; j++) {
            float vv = acc[i][j] + badd[j];
            if (relu) vv = fmaxf(vv, 0.f);
            op[j] = vv;
        }
        *(float4*)&C[(size_t)row * N + n0 + tx*4] = o;
    }
}

// ---------------------------------------------------------------------------
// PoPE: q,k (B,S,D) -> q_pope,k_pope (B,H,S,128) with softplus magnitudes and
// phases = pos*freq + phase_bias. (positions input == arange(S); use s.)
// ---------------------------------------------------------------------------
__global__ __launch_bounds__(256) void pope_kernel(
    const float* __restrict__ q, const float* __restrict__ k,
    const float* __restrict__ phase_bias, const float* __restrict__ freqs,
    float* __restrict__ qp, float* __restrict__ kp)
{
    int idx = blockIdx.x * 256 + threadIdx.x;   // over B*H*S*HD = 4M
    int d = idx & 63;
    int s = (idx >> 6) & (S_ - 1);
    int h = (idx >> 17) & (H_ - 1);
    int b = idx >> 21;

    size_t src = (size_t)(b * S_ + s) * D_ + h * HD_ + d;
    float muq = softplus_f(q[src]);
    float muk = softplus_f(k[src]);

    float ph = (float)s * freqs[d] + phase_bias[h * HD_ + d];
    float sn, cs;
    sincosf(ph, &sn, &cs);

    size_t o = ((size_t)(b * H_ + h) * S_ + s) * 128 + d;
    qp[o]      = muq * cs;
    qp[o + 64] = muq * sn;
    kp[o]      = muk * cs;
    kp[o + 64] = muk * sn;
}

// ---------------------------------------------------------------------------
// Causal attention with softmax1: one wave per query row.
// Score phase: lane = key index (each lane dots q(128) with one k row).
// PV phase:    lane = v dim (hd=64 == wave width).
// out = acc / (1 + l)  with online running max.
// ---------------------------------------------------------------------------
__global__ __launch_bounds__(256) void attn_kernel(
    const float* __restrict__ qp, const float* __restrict__ kp,
    const float* __restrict__ v, float* __restrict__ ao)
{
    __shared__ float qs[4][128];
    __shared__ float es[4][64];

    const int w    = threadIdx.x >> 6;   // wave 0..3
    const int lane = threadIdx.x & 63;
    const int bh   = blockIdx.y;         // 0..B*H-1
    const int b    = bh >> 4;
    const int h    = bh & 15;
    const int s    = blockIdx.x * 4 + w; // query row
    const float scale = 0.08838834764831845f;  // 1/sqrt(128)

    size_t qrow = ((size_t)bh * S_ + s) * 128;
    qs[w][lane]      = qp[qrow + lane];
    qs[w][lane + 64] = qp[qrow + lane + 64];

    float m = -INFINITY, l = 0.f, acc = 0.f;
    const float4* qs4 = (const float4*)qs[w];

    for (int t0 = 0; t0 <= s; t0 += 64) {
        int nk = min(64, s + 1 - t0);

        // --- score phase: lane j computes q . k[t0+j] ---
        float sc = -INFINITY;
        if (lane < nk) {
            const float4* krow = (const float4*)(kp + ((size_t)bh * S_ + t0 + lane) * 128);
            float dot = 0.f;
            #pragma unroll 8
            for (int d4 = 0; d4 < 32; d4++) {
                float4 qv = qs4[d4];
                float4 kv = krow[d4];
                dot += qv.x*kv.x + qv.y*kv.y + qv.z*kv.z + qv.w*kv.w;
            }
            sc = dot * scale;
        }

        // wave max
        float cmax = sc;
        #pragma unroll
        for (int off = 32; off >= 1; off >>= 1)
            cmax = fmaxf(cmax, __shfl_xor(cmax, off, 64));
        float mnew  = fmaxf(m, cmax);
        float alpha = expf(m - mnew);     // first chunk: exp(-inf)=0

        float e = (lane < nk) ? expf(sc - mnew) : 0.f;
        float csum = e;
        #pragma unroll
        for (int off = 32; off >= 1; off >>= 1)
            csum += __shfl_xor(csum, off, 64);
        l = l * alpha + csum;

        es[w][lane] = e;   // wave-local LDS; DS ops in-order within a wave

        // --- PV phase: lane = output dim ---
        float a2 = 0.f;
        const float* vbase = v + ((size_t)b * S_ + t0) * D_ + h * HD_ + lane;
        #pragma unroll 8
        for (int j = 0; j < 64; j++) {
            a2 += es[w][j] * vbase[(size_t)j * D_];
        }
        acc = acc * alpha + a2;
        m = mnew;
    }

    ao[((size_t)b * S_ + s) * D_ + h * HD_ + lane] = acc / (1.f + l);
}

// ---------------------------------------------------------------------------
// Residual + LayerNorm: out = LN(y + res) * g + beta. One block per row.
// ---------------------------------------------------------------------------
__global__ __launch_bounds__(256) void ln_kernel(
    const float* __restrict__ y, const float* __restrict__ res,
    const float* __restrict__ g, const float* __restrict__ beta,
    float* __restrict__ out)
{
    const int row = blockIdx.x;
    const int tid = threadIdx.x;
    const float* yr = y   + (size_t)row * D_;
    const float* rr = res + (size_t)row * D_;

    float t[4];
    float sum = 0.f, sumsq = 0.f;
    #pragma unroll
    for (int i = 0; i < 4; i++) {
        int c = tid + 256*i;
        t[i] = yr[c] + rr[c];
        sum   += t[i];
        sumsq += t[i]*t[i];
    }
    #pragma unroll
    for (int off = 32; off >= 1; off >>= 1) {
        sum   += __shfl_xor(sum,   off, 64);
        sumsq += __shfl_xor(sumsq, off, 64);
    }
    __shared__ float rs_[4], rq_[4];
    int w = tid >> 6, lane = tid & 63;
    if (lane == 0) { rs_[w] = sum; rq_[w] = sumsq; }
    __syncthreads();
    float tot  = rs_[0] + rs_[1] + rs_[2] + rs_[3];
    float totq = rq_[0] + rq_[1] + rq_[2] + rq_[3];
    float mu   = tot  * (1.f / D_);
    float var  = totq * (1.f / D_) - mu * mu;
    float rstd = rsqrtf(var + 1e-5f);

    float* orow = out + (size_t)row * D_;
    #pragma unroll
    for (int i = 0; i < 4; i++) {
        int c = tid + 256*i;
        orow[c] = (t[i] - mu) * rstd * g[c] + beta[c];
    }
}

// ---------------------------------------------------------------------------
extern "C" void kernel_launch(void* const* d_in, const int* in_sizes, int n_in,
                              void* d_out, int out_size, void* d_ws, size_t ws_size,
                              hipStream_t stream)
{
    const float* x   = (const float*)d_in[0];
    // d_in[1] = positions (== arange(S), used implicitly)
    const float* Wq  = (const float*)d_in[2];
    const float* bq  = (const float*)d_in[3];
    const float* Wk  = (const float*)d_in[4];
    const float* bk  = (const float*)d_in[5];
    const float* Wv  = (const float*)d_in[6];
    const float* bv  = (const float*)d_in[7];
    const float* Wo  = (const float*)d_in[8];
    const float* bo  = (const float*)d_in[9];
    const float* phase_bias = (const float*)d_in[10];
    const float* freqs = (const float*)d_in[11];
    const float* W1  = (const float*)d_in[12];
    const float* b1  = (const float*)d_in[13];
    const float* W2  = (const float*)d_in[14];
    const float* b2  = (const float*)d_in[15];
    const float* g1  = (const float*)d_in[16];
    const float* be1 = (const float*)d_in[17];
    const float* g2  = (const float*)d_in[18];
    const float* be2 = (const float*)d_in[19];
    float* out = (float*)d_out;

    // Workspace layout (floats). Peak use: 36M floats = 144 MB.
    float* ws = (float*)d_ws;
    const size_t MG = 1024 * 1024;
    float* q  = ws;             // 4M  (B,S,D)
    float* k  = ws + 4*MG;      // 4M
    float* v  = ws + 8*MG;      // 4M
    float* qp = ws + 12*MG;     // 8M  (B,H,S,128)
    float* kp = ws + 20*MG;     // 8M
    float* ao = ws + 28*MG;     // 4M  (B,S,D)
    float* x1 = ws + 32*MG;     // 4M
    float* hb = ws + 12*MG;     // 16M (B,S,DFF)  -- reuses qp/kp (dead after attention)
    float* p  = q;              // proj out, reuses q
    float* y2 = k;              // ffn out, reuses k

    dim3 blk(256);

    // QKV projections
    gemm_bias_kernel<<<dim3(D_/64, M_/64), blk, 0, stream>>>(x, Wq, bq, q, M_, D_, D_, 0);
    gemm_bias_kernel<<<dim3(D_/64, M_/64), blk, 0, stream>>>(x, Wk, bk, k, M_, D_, D_, 0);
    gemm_bias_kernel<<<dim3(D_/64, M_/64), blk, 0, stream>>>(x, Wv, bv, v, M_, D_, D_, 0);

    // PoPE
    pope_kernel<<<dim3((B_*H_*S_*HD_)/256), blk, 0, stream>>>(q, k, phase_bias, freqs, qp, kp);

    // Attention (flash-style, softmax1)
    attn_kernel<<<dim3(S_/4, B_*H_), blk, 0, stream>>>(qp, kp, v, ao);

    // Output projection + residual LN
    gemm_bias_kernel<<<dim3(D_/64, M_/64), blk, 0, stream>>>(ao, Wo, bo, p, M_, D_, D_, 0);
    ln_kernel<<<dim3(M_), blk, 0, stream>>>(p, x, g1, be1, x1);

    // FFN
    gemm_bias_kernel<<<dim3(DFF_/64, M_/64), blk, 0, stream>>>(x1, W1, b1, hb, M_, D_, DFF_, 1);
    gemm_bias_kernel<<<dim3(D_/64, M_/64), blk, 0, stream>>>(hb, W2, b2, y2, M_, DFF_, D_, 0);
    ln_kernel<<<dim3(M_), blk, 0, stream>>>(y2, x1, g2, be2, out);
}

// Round 2
// 1234.311 us; speedup vs baseline: 4.9963x; 4.9963x over previous
//
#include <hip/hip_runtime.h>
#include <hip/hip_bf16.h>
#include <math.h>

#define B_   2
#define S_   2048
#define D_   1024
#define H_   16
#define HD_  64
#define DFF_ 4096
#define M_   (B_*S_)   // 4096 rows

typedef __attribute__((ext_vector_type(8))) short bf16x8;
typedef __attribute__((ext_vector_type(4))) float f32x4;

#define MFMA16(a,b,c) __builtin_amdgcn_mfma_f32_16x16x32_bf16((a),(b),(c),0,0,0)

__device__ __forceinline__ unsigned short f2b(float f) {
    union { float f; unsigned u; } v; v.f = f;
    return (unsigned short)((v.u + 0x7FFFu + ((v.u >> 16) & 1u)) >> 16);
}
__device__ __forceinline__ float softplus_f(float x) {
    return fmaxf(x, 0.f) + log1pf(__expf(-fabsf(x)));
}

// ---------------------------------------------------------------------------
// fp32 -> bf16 elementwise convert
// ---------------------------------------------------------------------------
__global__ __launch_bounds__(256) void conv_bf16_kernel(
    const float* __restrict__ in, unsigned short* __restrict__ out)
{
    int i = blockIdx.x * 256 + threadIdx.x;
    out[i] = f2b(in[i]);
}

// ---------------------------------------------------------------------------
// Weight transpose + bf16: W[K][N] fp32 -> WT[N][K] bf16
// ---------------------------------------------------------------------------
__global__ __launch_bounds__(256) void wtrans_kernel(
    const float* __restrict__ W, unsigned short* __restrict__ WT, int K, int N)
{
    __shared__ float tile[32][33];
    const int n0 = blockIdx.x * 32, k0 = blockIdx.y * 32;
    const int tx = threadIdx.x & 31, ty = threadIdx.x >> 5;  // ty 0..7
    #pragma unroll
    for (int i = 0; i < 4; i++) {
        tile[ty + 8*i][tx] = W[(size_t)(k0 + ty + 8*i) * N + n0 + tx];
    }
    __syncthreads();
    #pragma unroll
    for (int i = 0; i < 4; i++) {
        WT[(size_t)(n0 + ty + 8*i) * K + k0 + tx] = f2b(tile[tx][ty + 8*i]);
    }
}

// ---------------------------------------------------------------------------
// bf16 MFMA GEMM: C[M,N] = A[M,K](bf16) @ WT[N,K](bf16)^T + bias, opt relu.
// 64x64 C tile, 4 waves (2x2), each wave 32x32 via 2x2 mfma_16x16x32 frags.
// A-frags and B-frags loaded directly from global (contiguous 16B per lane).
// Outputs fp32 and/or bf16.
// C/D layout: col=lane&15, row=quad*4+reg.  A: A[m=lane&15][k=quad*8+j].
// ---------------------------------------------------------------------------
__global__ __launch_bounds__(256) void gemm_bf16_kernel(
    const unsigned short* __restrict__ A,
    const unsigned short* __restrict__ WT,
    const float* __restrict__ bias,
    float* __restrict__ outF, unsigned short* __restrict__ outB,
    int M, int K, int N, int relu)
{
    const int tid  = threadIdx.x;
    const int w    = tid >> 6, lane = tid & 63;
    const int quad = lane >> 4, l16 = lane & 15;
    const int m_base = blockIdx.y * 64 + (w >> 1) * 32;
    const int n_base = blockIdx.x * 64 + (w & 1) * 32;

    const unsigned short* a0p = A  + (size_t)(m_base + l16) * K + quad * 8;
    const unsigned short* a1p = a0p + (size_t)16 * K;
    const unsigned short* b0p = WT + (size_t)(n_base + l16) * K + quad * 8;
    const unsigned short* b1p = b0p + (size_t)16 * K;

    f32x4 acc00 = {0,0,0,0}, acc01 = {0,0,0,0}, acc10 = {0,0,0,0}, acc11 = {0,0,0,0};

    for (int k0 = 0; k0 < K; k0 += 32) {
        bf16x8 a0 = *(const bf16x8*)(a0p + k0);
        bf16x8 a1 = *(const bf16x8*)(a1p + k0);
        bf16x8 b0 = *(const bf16x8*)(b0p + k0);
        bf16x8 b1 = *(const bf16x8*)(b1p + k0);
        acc00 = MFMA16(a0, b0, acc00);
        acc01 = MFMA16(a0, b1, acc01);
        acc10 = MFMA16(a1, b0, acc10);
        acc11 = MFMA16(a1, b1, acc11);
    }

    const float bias0 = bias[n_base + l16];
    const float bias1 = bias[n_base + 16 + l16];

    #pragma unroll
    for (int mt = 0; mt < 2; mt++) {
        #pragma unroll
        for (int nt = 0; nt < 2; nt++) {
            const f32x4 acc = (mt == 0) ? (nt == 0 ? acc00 : acc01)
                                        : (nt == 0 ? acc10 : acc11);
            const float bv = nt == 0 ? bias0 : bias1;
            const int n = n_base + nt * 16 + l16;
            #pragma unroll
            for (int r = 0; r < 4; r++) {
                const int m = m_base + mt * 16 + quad * 4 + r;
                float val = acc[r] + bv;
                if (relu) val = fmaxf(val, 0.f);
                const size_t idx = (size_t)m * N + n;
                if (outF) outF[idx] = val;
                if (outB) outB[idx] = f2b(val);
            }
        }
    }
}

// ---------------------------------------------------------------------------
// PoPE: q,k fp32 (B,S,D) -> bf16 qp,kp (B*H, S, 128)
// ---------------------------------------------------------------------------
__global__ __launch_bounds__(256) void pope_kernel(
    const float* __restrict__ q, const float* __restrict__ k,
    const float* __restrict__ phase_bias, const float* __restrict__ freqs,
    unsigned short* __restrict__ qp, unsigned short* __restrict__ kp)
{
    int idx = blockIdx.x * 256 + threadIdx.x;   // over B*H*S*HD = 4M
    int d = idx & 63;
    int s = (idx >> 6) & (S_ - 1);
    int h = (idx >> 17) & (H_ - 1);
    int b = idx >> 21;

    size_t src = (size_t)(b * S_ + s) * D_ + h * HD_ + d;
    float muq = softplus_f(q[src]);
    float muk = softplus_f(k[src]);

    float ph = (float)s * freqs[d] + phase_bias[h * HD_ + d];
    float sn, cs;
    sincosf(ph, &sn, &cs);

    size_t o = ((size_t)(b * H_ + h) * S_ + s) * 128 + d;
    qp[o]      = f2b(muq * cs);
    qp[o + 64] = f2b(muq * sn);
    kp[o]      = f2b(muk * cs);
    kp[o + 64] = f2b(muk * sn);
}

// ---------------------------------------------------------------------------
// V transpose: v fp32 (B,S,D) -> vt bf16 (B*H, 64, S)
// ---------------------------------------------------------------------------
__global__ __launch_bounds__(256) void vtrans_kernel(
    const float* __restrict__ v, unsigned short* __restrict__ vt)
{
    __shared__ float tile[64][65];
    const int bh = blockIdx.y, b = bh >> 4, h = bh & 15;
    const int s0 = blockIdx.x * 64;
    const int tid = threadIdx.x;
    #pragma unroll
    for (int i = 0; i < 16; i++) {
        int idx = i * 256 + tid;
        int s = idx >> 6, d = idx & 63;
        tile[s][d] = v[(size_t)(b * S_ + s0 + s) * D_ + h * HD_ + d];
    }
    __syncthreads();
    #pragma unroll
    for (int i = 0; i < 16; i++) {
        int idx = i * 256 + tid;
        int d = idx >> 6, s = idx & 63;
        vt[((size_t)bh * 64 + d) * S_ + s0 + s] = f2b(tile[s][d]);
    }
}

// ---------------------------------------------------------------------------
// MFMA flash attention with softmax1. One wave per 16 query rows.
// QK^T: A=Q-frags (regs), B=K rows (global 16B). Online softmax in C-layout.
// P -> A-layout via wave-private padded LDS. PV: B=vt rows (global 16B).
// OOB tail keys index-clamped (all provably masked, e=0).
// ---------------------------------------------------------------------------
__global__ __launch_bounds__(256) void attn_mfma_kernel(
    const unsigned short* __restrict__ qp,
    const unsigned short* __restrict__ kp,
    const unsigned short* __restrict__ vt,
    unsigned short* __restrict__ ao)
{
    __shared__ unsigned short p_lds[4][16][40];   // per-wave, stride 40 bf16 (16B-aligned rows)

    const int tid  = threadIdx.x;
    const int w    = tid >> 6, lane = tid & 63;
    const int quad = lane >> 4, l16 = lane & 15;
    const int bh = blockIdx.y;
    const int b = bh >> 4, h = bh & 15;
    // reversed x so longest-running blocks dispatch first
    const int q0 = (gridDim.x - 1 - blockIdx.x) * 64 + w * 16;
    const float scale = 0.08838834764831845f;   // 1/sqrt(128)

    const unsigned short* qbase = qp + ((size_t)bh * S_ + q0 + l16) * 128 + quad * 8;
    bf16x8 qa0 = *(const bf16x8*)(qbase);
    bf16x8 qa1 = *(const bf16x8*)(qbase + 32);
    bf16x8 qa2 = *(const bf16x8*)(qbase + 64);
    bf16x8 qa3 = *(const bf16x8*)(qbase + 96);

    f32x4 o0 = {0,0,0,0}, o1 = {0,0,0,0}, o2 = {0,0,0,0}, o3 = {0,0,0,0};
    float m_run[4] = {-1e30f, -1e30f, -1e30f, -1e30f};
    float l_run[4] = {0.f, 0.f, 0.f, 0.f};

    const int qmax = q0 + 15;
    for (int t0 = 0; t0 <= qmax; t0 += 32) {
        const int kr0 = min(t0 + l16, S_ - 1);
        const int kr1 = min(t0 + 16 + l16, S_ - 1);
        const unsigned short* k0p = kp + ((size_t)bh * S_ + kr0) * 128 + quad * 8;
        const unsigned short* k1p = kp + ((size_t)bh * S_ + kr1) * 128 + quad * 8;

        f32x4 s0 = {0,0,0,0}, s1 = {0,0,0,0};
        s0 = MFMA16(qa0, *(const bf16x8*)(k0p),      s0);
        s1 = MFMA16(qa0, *(const bf16x8*)(k1p),      s1);
        s0 = MFMA16(qa1, *(const bf16x8*)(k0p + 32), s0);
        s1 = MFMA16(qa1, *(const bf16x8*)(k1p + 32), s1);
        s0 = MFMA16(qa2, *(const bf16x8*)(k0p + 64), s0);
        s1 = MFMA16(qa2, *(const bf16x8*)(k1p + 64), s1);
        s0 = MFMA16(qa3, *(const bf16x8*)(k0p + 96), s0);
        s1 = MFMA16(qa3, *(const bf16x8*)(k1p + 96), s1);

        const int key0 = t0 + l16, key1 = t0 + 16 + l16;
        float e0[4], e1[4], alpha[4];
        #pragma unroll
        for (int r = 0; r < 4; r++) {
            const int qrow = q0 + quad * 4 + r;
            float v0 = (key0 <= qrow) ? s0[r] * scale : -1e30f;
            float v1 = (key1 <= qrow) ? s1[r] * scale : -1e30f;
            float mx = fmaxf(v0, v1);
            #pragma unroll
            for (int off = 8; off >= 1; off >>= 1)
                mx = fmaxf(mx, __shfl_xor(mx, off, 64));
            const float mnew = fmaxf(m_run[r], mx);
            alpha[r] = __expf(m_run[r] - mnew);
            const float ee0 = __expf(v0 - mnew);
            const float ee1 = __expf(v1 - mnew);
            float ls = ee0 + ee1;
            #pragma unroll
            for (int off = 8; off >= 1; off >>= 1)
                ls += __shfl_xor(ls, off, 64);
            l_run[r] = l_run[r] * alpha[r] + ls;
            m_run[r] = mnew;
            e0[r] = ee0; e1[r] = ee1;
        }

        #pragma unroll
        for (int r = 0; r < 4; r++) {
            const int row = quad * 4 + r;
            p_lds[w][row][l16]      = f2b(e0[r]);
            p_lds[w][row][l16 + 16] = f2b(e1[r]);
        }
        asm volatile("s_waitcnt lgkmcnt(0)" ::: "memory");
        bf16x8 pa = *(const bf16x8*)(&p_lds[w][l16][quad * 8]);

        #pragma unroll
        for (int r = 0; r < 4; r++) {
            o0[r] *= alpha[r]; o1[r] *= alpha[r];
            o2[r] *= alpha[r]; o3[r] *= alpha[r];
        }

        const int ks = min(t0 + quad * 8, S_ - 8);
        const unsigned short* vb = vt + ((size_t)bh * 64 + l16) * S_ + ks;
        o0 = MFMA16(pa, *(const bf16x8*)(vb),           o0);
        o1 = MFMA16(pa, *(const bf16x8*)(vb + 16 * S_), o1);
        o2 = MFMA16(pa, *(const bf16x8*)(vb + 32 * S_), o2);
        o3 = MFMA16(pa, *(const bf16x8*)(vb + 48 * S_), o3);
    }

    #pragma unroll
    for (int r = 0; r < 4; r++) {
        const int row = q0 + quad * 4 + r;
        const float inv = 1.f / (1.f + l_run[r]);
        const size_t base = (size_t)(b * S_ + row) * D_ + h * HD_ + l16;
        ao[base]      = f2b(o0[r] * inv);
        ao[base + 16] = f2b(o1[r] * inv);
        ao[base + 32] = f2b(o2[r] * inv);
        ao[base + 48] = f2b(o3[r] * inv);
    }
}

// ---------------------------------------------------------------------------
// Residual + LayerNorm; optional secondary bf16 output.
// ---------------------------------------------------------------------------
__global__ __launch_bounds__(256) void ln_kernel(
    const float* __restrict__ y, const float* __restrict__ res,
    const float* __restrict__ g, const float* __restrict__ beta,
    float* __restrict__ out, unsigned short* __restrict__ outB)
{
    const int row = blockIdx.x;
    const int tid = threadIdx.x;
    const float* yr = y   + (size_t)row * D_;
    const float* rr = res + (size_t)row * D_;

    float t[4];
    float sum = 0.f, sumsq = 0.f;
    #pragma unroll
    for (int i = 0; i < 4; i++) {
        int c = tid + 256 * i;
        t[i] = yr[c] + rr[c];
        sum   += t[i];
        sumsq += t[i] * t[i];
    }
    #pragma unroll
    for (int off = 32; off >= 1; off >>= 1) {
        sum   += __shfl_xor(sum,   off, 64);
        sumsq += __shfl_xor(sumsq, off, 64);
    }
    __shared__ float rs_[4], rq_[4];
    int w = tid >> 6, lane = tid & 63;
    if (lane == 0) { rs_[w] = sum; rq_[w] = sumsq; }
    __syncthreads();
    float tot  = rs_[0] + rs_[1] + rs_[2] + rs_[3];
    float totq = rq_[0] + rq_[1] + rq_[2] + rq_[3];
    float mu   = tot  * (1.f / D_);
    float var  = totq * (1.f / D_) - mu * mu;
    float rstd = rsqrtf(var + 1e-5f);

    float* orow = out + (size_t)row * D_;
    #pragma unroll
    for (int i = 0; i < 4; i++) {
        int c = tid + 256 * i;
        float val = (t[i] - mu) * rstd * g[c] + beta[c];
        orow[c] = val;
        if (outB) outB[(size_t)row * D_ + c] = f2b(val);
    }
}

// ---------------------------------------------------------------------------
extern "C" void kernel_launch(void* const* d_in, const int* in_sizes, int n_in,
                              void* d_out, int out_size, void* d_ws, size_t ws_size,
                              hipStream_t stream)
{
    const float* x   = (const float*)d_in[0];
    const float* Wq  = (const float*)d_in[2];
    const float* bq  = (const float*)d_in[3];
    const float* Wk  = (const float*)d_in[4];
    const float* bk  = (const float*)d_in[5];
    const float* Wv  = (const float*)d_in[6];
    const float* bv  = (const float*)d_in[7];
    const float* Wo  = (const float*)d_in[8];
    const float* bo  = (const float*)d_in[9];
    const float* phase_bias = (const float*)d_in[10];
    const float* freqs = (const float*)d_in[11];
    const float* W1  = (const float*)d_in[12];
    const float* b1  = (const float*)d_in[13];
    const float* W2  = (const float*)d_in[14];
    const float* b2  = (const float*)d_in[15];
    const float* g1  = (const float*)d_in[16];
    const float* be1 = (const float*)d_in[17];
    const float* g2  = (const float*)d_in[18];
    const float* be2 = (const float*)d_in[19];
    float* out = (float*)d_out;

    char* base = (char*)d_ws;
    const size_t MiB = 1024 * 1024;
    unsigned short* WqT = (unsigned short*)(base);              // 2 MiB
    unsigned short* WkT = (unsigned short*)(base + 2  * MiB);
    unsigned short* WvT = (unsigned short*)(base + 4  * MiB);
    unsigned short* WoT = (unsigned short*)(base + 6  * MiB);
    unsigned short* W1T = (unsigned short*)(base + 8  * MiB);   // 8 MiB
    unsigned short* W2T = (unsigned short*)(base + 16 * MiB);   // 8 MiB
    unsigned short* xb  = (unsigned short*)(base + 24 * MiB);   // 8 MiB  [later x1b]
    float* qf = (float*)(base + 32 * MiB);                      // 16 MiB [later p]
    float* kf = (float*)(base + 48 * MiB);                      // 16 MiB [later x1]
    float* vf = (float*)(base + 64 * MiB);                      // 16 MiB [later y2]
    unsigned short* qpb = (unsigned short*)(base + 80  * MiB);  // 16 MiB [hb lower]
    unsigned short* kpb = (unsigned short*)(base + 96  * MiB);  // 16 MiB [hb upper]
    unsigned short* vtb = (unsigned short*)(base + 112 * MiB);  // 8 MiB
    unsigned short* aob = (unsigned short*)(base + 120 * MiB);  // 8 MiB
    float* pf  = qf;
    float* x1  = kf;
    float* y2  = vf;
    unsigned short* x1b = xb;
    unsigned short* hb  = qpb;  // 32 MiB spans qpb+kpb

    dim3 blk(256);

    // prep: x -> bf16, weights -> transposed bf16
    conv_bf16_kernel<<<dim3(M_ * D_ / 256), blk, 0, stream>>>(x, xb);
    wtrans_kernel<<<dim3(32, 32), blk, 0, stream>>>(Wq, WqT, D_, D_);
    wtrans_kernel<<<dim3(32, 32), blk, 0, stream>>>(Wk, WkT, D_, D_);
    wtrans_kernel<<<dim3(32, 32), blk, 0, stream>>>(Wv, WvT, D_, D_);
    wtrans_kernel<<<dim3(32, 32), blk, 0, stream>>>(Wo, WoT, D_, D_);
    wtrans_kernel<<<dim3(DFF_ / 32, D_ / 32), blk, 0, stream>>>(W1, W1T, D_, DFF_);
    wtrans_kernel<<<dim3(D_ / 32, DFF_ / 32), blk, 0, stream>>>(W2, W2T, DFF_, D_);

    // QKV projections (fp32 out)
    gemm_bf16_kernel<<<dim3(D_ / 64, M_ / 64), blk, 0, stream>>>(xb, WqT, bq, qf, nullptr, M_, D_, D_, 0);
    gemm_bf16_kernel<<<dim3(D_ / 64, M_ / 64), blk, 0, stream>>>(xb, WkT, bk, kf, nullptr, M_, D_, D_, 0);
    gemm_bf16_kernel<<<dim3(D_ / 64, M_ / 64), blk, 0, stream>>>(xb, WvT, bv, vf, nullptr, M_, D_, D_, 0);

    // PoPE (bf16 out) + V transpose (bf16 out)
    pope_kernel<<<dim3(B_ * H_ * S_ * HD_ / 256), blk, 0, stream>>>(qf, kf, phase_bias, freqs, qpb, kpb);
    vtrans_kernel<<<dim3(S_ / 64, B_ * H_), blk, 0, stream>>>(vf, vtb);

    // Flash attention (bf16 out)
    attn_mfma_kernel<<<dim3(S_ / 64, B_ * H_), blk, 0, stream>>>(qpb, kpb, vtb, aob);

    // Output projection + LN1 (fp32 + bf16 out)
    gemm_bf16_kernel<<<dim3(D_ / 64, M_ / 64), blk, 0, stream>>>(aob, WoT, bo, pf, nullptr, M_, D_, D_, 0);
    ln_kernel<<<dim3(M_), blk, 0, stream>>>(pf, x, g1, be1, x1, x1b);

    // FFN
    gemm_bf16_kernel<<<dim3(DFF_ / 64, M_ / 64), blk, 0, stream>>>(x1b, W1T, b1, nullptr, hb, M_, D_, DFF_, 1);
    gemm_bf16_kernel<<<dim3(D_ / 64, M_ / 64), blk, 0, stream>>>(hb, W2T, b2, y2, nullptr, M_, DFF_, D_, 0);
    ln_kernel<<<dim3(M_), blk, 0, stream>>>(y2, x1, g2, be2, out, nullptr);
}

// Round 4
// 572.669 us; speedup vs baseline: 10.7688x; 2.1554x over previous
//
#include <hip/hip_runtime.h>
#include <hip/hip_bf16.h>
#include <math.h>

#define B_   2
#define S_   2048
#define D_   1024
#define H_   16
#define HD_  64
#define DFF_ 4096
#define M_   (B_*S_)   // 4096 rows

typedef __attribute__((ext_vector_type(8))) short bf16x8;
typedef __attribute__((ext_vector_type(4))) float f32x4;

#define MFMA16(a,b,c) __builtin_amdgcn_mfma_f32_16x16x32_bf16((a),(b),(c),0,0,0)

__device__ __forceinline__ unsigned short f2b(float f) {
    union { float f; unsigned u; } v; v.f = f;
    return (unsigned short)((v.u + 0x7FFFu + ((v.u >> 16) & 1u)) >> 16);
}
__device__ __forceinline__ float softplus_f(float x) {
    return fmaxf(x, 0.f) + log1pf(__expf(-fabsf(x)));
}
// async global->LDS, 16B per lane. LDS dest = base + lane*16 (wave-uniform base).
__device__ __forceinline__ void g2l16(const void* g, void* l) {
    __builtin_amdgcn_global_load_lds(
        (const __attribute__((address_space(1))) unsigned int*)g,
        (__attribute__((address_space(3))) unsigned int*)l, 16, 0, 0);
}

// ---------------------------------------------------------------------------
// fp32 -> bf16 elementwise
// ---------------------------------------------------------------------------
__global__ __launch_bounds__(256) void conv_bf16_kernel(
    const float* __restrict__ in, unsigned short* __restrict__ out)
{
    int i = blockIdx.x * 256 + threadIdx.x;
    out[i] = f2b(in[i]);
}

// ---------------------------------------------------------------------------
// Weight transpose + bf16: W[K][N] fp32 -> WT[N][K] bf16
// ---------------------------------------------------------------------------
__global__ __launch_bounds__(256) void wtrans_kernel(
    const float* __restrict__ W, unsigned short* __restrict__ WT, int K, int N)
{
    __shared__ float tile[32][33];
    const int n0 = blockIdx.x * 32, k0 = blockIdx.y * 32;
    const int tx = threadIdx.x & 31, ty = threadIdx.x >> 5;  // ty 0..7
    #pragma unroll
    for (int i = 0; i < 4; i++)
        tile[ty + 8*i][tx] = W[(size_t)(k0 + ty + 8*i) * N + n0 + tx];
    __syncthreads();
    #pragma unroll
    for (int i = 0; i < 4; i++)
        WT[(size_t)(n0 + ty + 8*i) * K + k0 + tx] = f2b(tile[tx][ty + 8*i]);
}

// ---------------------------------------------------------------------------
// bias concat (bq|bk|bv) -> 3072
// ---------------------------------------------------------------------------
__global__ __launch_bounds__(256) void bcat_kernel(
    const float* __restrict__ a, const float* __restrict__ b,
    const float* __restrict__ c, float* __restrict__ o)
{
    int i = blockIdx.x * 256 + threadIdx.x;
    o[i] = (i < 1024) ? a[i] : (i < 2048 ? b[i - 1024] : c[i - 2048]);
}

// ---------------------------------------------------------------------------
// m97-style bf16 MFMA GEMM: C[M,N] = A[M,K] @ WT[N,K]^T + bias, opt relu.
// 128x128 tile, BK=32, 4 waves (2x2) each 64x64 (4x4 frags of 16x16x32).
// Staging via global_load_lds width=16; LDS tiles [128][32] row-major.
// ---------------------------------------------------------------------------
__global__ __launch_bounds__(256) void gemm_bf16_kernel(
    const unsigned short* __restrict__ A,
    const unsigned short* __restrict__ WT,
    const float* __restrict__ bias,
    float* __restrict__ outF, unsigned short* __restrict__ outB,
    int M, int K, int N, int relu)
{
    __shared__ unsigned short As[128 * 32];
    __shared__ unsigned short Bs[128 * 32];

    const int tid = threadIdx.x;
    const int w = tid >> 6, lane = tid & 63;
    const int quad = lane >> 4, l16 = lane & 15;
    const size_t m0 = (size_t)blockIdx.y * 128, n0 = (size_t)blockIdx.x * 128;
    const int wm = (w >> 1) * 64, wn = (w & 1) * 64;

    // staging: per wave 2 instrs each for A and B; instr j covers 16 rows.
    const int srow = w * 32 + (lane >> 2);
    const int schunk = (lane & 3) * 8;
    const unsigned short* ga = A  + (m0 + srow) * K + schunk;
    const unsigned short* gb = WT + (n0 + srow) * K + schunk;
    unsigned short* lA0 = &As[(w * 32) * 32];
    unsigned short* lA1 = &As[(w * 32 + 16) * 32];
    unsigned short* lB0 = &Bs[(w * 32) * 32];
    unsigned short* lB1 = &Bs[(w * 32 + 16) * 32];
    const size_t K16 = (size_t)16 * K;

    f32x4 acc[4][4] = {};

    for (int k0 = 0; k0 < K; k0 += 32) {
        g2l16(ga + k0,       lA0);
        g2l16(ga + K16 + k0, lA1);
        g2l16(gb + k0,       lB0);
        g2l16(gb + K16 + k0, lB1);
        __syncthreads();

        bf16x8 af[4], bfr[4];
        #pragma unroll
        for (int t = 0; t < 4; t++) {
            af[t]  = *(const bf16x8*)&As[(wm + t * 16 + l16) * 32 + quad * 8];
            bfr[t] = *(const bf16x8*)&Bs[(wn + t * 16 + l16) * 32 + quad * 8];
        }
        #pragma unroll
        for (int mt = 0; mt < 4; mt++)
            #pragma unroll
            for (int nt = 0; nt < 4; nt++)
                acc[mt][nt] = MFMA16(af[mt], bfr[nt], acc[mt][nt]);
        __syncthreads();
    }

    float bv[4];
    #pragma unroll
    for (int nt = 0; nt < 4; nt++) bv[nt] = bias[n0 + wn + nt * 16 + l16];

    #pragma unroll
    for (int mt = 0; mt < 4; mt++) {
        #pragma unroll
        for (int nt = 0; nt < 4; nt++) {
            const size_t n = n0 + wn + nt * 16 + l16;
            #pragma unroll
            for (int r = 0; r < 4; r++) {
                const size_t m = m0 + wm + mt * 16 + quad * 4 + r;
                float val = acc[mt][nt][r] + bv[nt];
                if (relu) val = fmaxf(val, 0.f);
                const size_t idx = m * N + n;
                if (outF) outF[idx] = val;
                if (outB) outB[idx] = f2b(val);
            }
        }
    }
}

// ---------------------------------------------------------------------------
// PoPE: qkv fp32 (B,S,3072) -> bf16 qp,kp (B*H, S, 128)
// ---------------------------------------------------------------------------
__global__ __launch_bounds__(256) void pope_kernel(
    const float* __restrict__ qkv,
    const float* __restrict__ phase_bias, const float* __restrict__ freqs,
    unsigned short* __restrict__ qp, unsigned short* __restrict__ kp)
{
    int idx = blockIdx.x * 256 + threadIdx.x;   // over B*H*S*HD = 4M
    int d = idx & 63;
    int s = (idx >> 6) & (S_ - 1);
    int h = (idx >> 17) & (H_ - 1);
    int b = idx >> 21;

    size_t src = (size_t)(b * S_ + s) * 3072 + h * HD_ + d;
    float muq = softplus_f(qkv[src]);
    float muk = softplus_f(qkv[src + 1024]);

    float ph = (float)s * freqs[d] + phase_bias[h * HD_ + d];
    float sn, cs;
    sincosf(ph, &sn, &cs);

    size_t o = ((size_t)(b * H_ + h) * S_ + s) * 128 + d;
    qp[o]      = f2b(muq * cs);
    qp[o + 64] = f2b(muq * sn);
    kp[o]      = f2b(muk * cs);
    kp[o + 64] = f2b(muk * sn);
}

// ---------------------------------------------------------------------------
// V transpose: qkv fp32 (B,S,3072) col 2048.. -> vt bf16 (B*H, 64, S)
// ---------------------------------------------------------------------------
__global__ __launch_bounds__(256) void vtrans_kernel(
    const float* __restrict__ qkv, unsigned short* __restrict__ vt)
{
    __shared__ float tile[64][65];
    const int bh = blockIdx.y, b = bh >> 4, h = bh & 15;
    const int s0 = blockIdx.x * 64;
    const int tid = threadIdx.x;
    #pragma unroll
    for (int i = 0; i < 16; i++) {
        int idx = i * 256 + tid;
        int s = idx >> 6, d = idx & 63;
        tile[s][d] = qkv[(size_t)(b * S_ + s0 + s) * 3072 + 2048 + h * HD_ + d];
    }
    __syncthreads();
    #pragma unroll
    for (int i = 0; i < 16; i++) {
        int idx = i * 256 + tid;
        int d = idx >> 6, s = idx & 63;
        vt[((size_t)bh * 64 + d) * S_ + s0 + s] = f2b(tile[s][d]);
    }
}

// ---------------------------------------------------------------------------
// MFMA flash attention with softmax1. Block = 64 q rows (4 waves x 16).
// K/V tiles (64 keys) staged in LDS via global_load_lds with XOR chunk
// swizzle (rows are 256B/128B: unswizzled would be 16-way bank conflict).
// ---------------------------------------------------------------------------
__global__ __launch_bounds__(256) void attn_mfma_kernel(
    const unsigned short* __restrict__ qp,
    const unsigned short* __restrict__ kp,
    const unsigned short* __restrict__ vt,
    unsigned short* __restrict__ ao)
{
    __shared__ unsigned short kt_lds[64][128];  // [key][k], 16B chunks swizzled by key&15
    __shared__ unsigned short vt_lds[64][64];   // [d][key], 16B chunks swizzled by d&7
    __shared__ unsigned short p_lds[4][16][72]; // per-wave P roundtrip (stride 144B)

    const int tid = threadIdx.x;
    const int w = tid >> 6, lane = tid & 63;
    const int quad = lane >> 4, l16 = lane & 15;
    const int bh = blockIdx.y, b = bh >> 4, h = bh & 15;
    const int q0b = (gridDim.x - 1 - blockIdx.x) * 64;  // big blocks dispatch first
    const int q0 = q0b + w * 16;
    const float scale = 0.08838834764831845f;   // 1/sqrt(128)

    const unsigned short* qbase = qp + ((size_t)bh * S_ + q0 + l16) * 128 + quad * 8;
    bf16x8 qa[4];
    #pragma unroll
    for (int kc = 0; kc < 4; kc++) qa[kc] = *(const bf16x8*)(qbase + kc * 32);

    f32x4 o[4] = {};
    float m_run[4] = {-1e30f, -1e30f, -1e30f, -1e30f};
    float l_run[4] = {0.f, 0.f, 0.f, 0.f};

    const int krow = lane >> 4, kslot = lane & 15;   // K staging: 4 rows/instr
    const int vrow = lane >> 3, vslot = lane & 7;    // V staging: 8 rows/instr

    for (int t0 = 0; t0 <= q0b; t0 += 64) {
        // --- stage K (64x128) ---
        #pragma unroll
        for (int j = 0; j < 4; j++) {
            int r = w * 16 + j * 4 + krow;
            int c = kslot ^ (r & 15);
            g2l16(kp + ((size_t)bh * S_ + t0 + r) * 128 + c * 8, &kt_lds[w * 16 + j * 4][0]);
        }
        // --- stage Vt (64x64) ---
        #pragma unroll
        for (int j = 0; j < 2; j++) {
            int d = w * 16 + j * 8 + vrow;
            int c = vslot ^ (d & 7);
            g2l16(vt + ((size_t)bh * 64 + d) * S_ + t0 + c * 8, &vt_lds[w * 16 + j * 8][0]);
        }
        __syncthreads();

        // --- QK^T: 16 q rows x 64 keys ---
        f32x4 sf[4];
        #pragma unroll
        for (int kg = 0; kg < 4; kg++) {
            f32x4 s = {0, 0, 0, 0};
            const int row = kg * 16 + l16;
            #pragma unroll
            for (int kc = 0; kc < 4; kc++) {
                const int slot = (kc * 4 + quad) ^ l16;
                s = MFMA16(qa[kc], *(const bf16x8*)&kt_lds[row][slot * 8], s);
            }
            sf[kg] = s;
        }

        // --- online softmax1 update ---
        float e[4][4], alpha[4];
        #pragma unroll
        for (int r = 0; r < 4; r++) {
            const int qrow = q0 + quad * 4 + r;
            float v0 = (t0 + l16      <= qrow) ? sf[0][r] * scale : -1e30f;
            float v1 = (t0 + 16 + l16 <= qrow) ? sf[1][r] * scale : -1e30f;
            float v2 = (t0 + 32 + l16 <= qrow) ? sf[2][r] * scale : -1e30f;
            float v3 = (t0 + 48 + l16 <= qrow) ? sf[3][r] * scale : -1e30f;
            float mx = fmaxf(fmaxf(v0, v1), fmaxf(v2, v3));
            #pragma unroll
            for (int off = 8; off >= 1; off >>= 1)
                mx = fmaxf(mx, __shfl_xor(mx, off, 64));
            const float mnew = fmaxf(m_run[r], mx);
            alpha[r] = __expf(m_run[r] - mnew);
            const float e0 = __expf(v0 - mnew), e1 = __expf(v1 - mnew);
            const float e2 = __expf(v2 - mnew), e3 = __expf(v3 - mnew);
            float ls = (e0 + e1) + (e2 + e3);
            #pragma unroll
            for (int off = 8; off >= 1; off >>= 1)
                ls += __shfl_xor(ls, off, 64);
            l_run[r] = l_run[r] * alpha[r] + ls;
            m_run[r] = mnew;
            e[r][0] = e0; e[r][1] = e1; e[r][2] = e2; e[r][3] = e3;
        }

        // --- P -> A-layout via per-wave LDS ---
        #pragma unroll
        for (int r = 0; r < 4; r++)
            #pragma unroll
            for (int kg = 0; kg < 4; kg++)
                p_lds[w][quad * 4 + r][kg * 16 + l16] = f2b(e[r][kg]);
        asm volatile("s_waitcnt lgkmcnt(0)" ::: "memory");
        bf16x8 pa0 = *(const bf16x8*)&p_lds[w][l16][quad * 8];
        bf16x8 pa1 = *(const bf16x8*)&p_lds[w][l16][quad * 8 + 32];

        #pragma unroll
        for (int r = 0; r < 4; r++) {
            o[0][r] *= alpha[r]; o[1][r] *= alpha[r];
            o[2][r] *= alpha[r]; o[3][r] *= alpha[r];
        }

        // --- PV ---
        #pragma unroll
        for (int dg = 0; dg < 4; dg++) {
            const int row = dg * 16 + l16;
            const int s0_ = quad ^ (l16 & 7);
            const int s1_ = (quad + 4) ^ (l16 & 7);
            o[dg] = MFMA16(pa0, *(const bf16x8*)&vt_lds[row][s0_ * 8], o[dg]);
            o[dg] = MFMA16(pa1, *(const bf16x8*)&vt_lds[row][s1_ * 8], o[dg]);
        }
        __syncthreads();
    }

    #pragma unroll
    for (int r = 0; r < 4; r++) {
        const int row = q0 + quad * 4 + r;
        const float inv = 1.f / (1.f + l_run[r]);
        const size_t base = (size_t)(b * S_ + row) * D_ + h * HD_ + l16;
        ao[base]      = f2b(o[0][r] * inv);
        ao[base + 16] = f2b(o[1][r] * inv);
        ao[base + 32] = f2b(o[2][r] * inv);
        ao[base + 48] = f2b(o[3][r] * inv);
    }
}

// ---------------------------------------------------------------------------
// Residual + LayerNorm; optional secondary bf16 output.
// ---------------------------------------------------------------------------
__global__ __launch_bounds__(256) void ln_kernel(
    const float* __restrict__ y, const float* __restrict__ res,
    const float* __restrict__ g, const float* __restrict__ beta,
    float* __restrict__ out, unsigned short* __restrict__ outB)
{
    const int row = blockIdx.x;
    const int tid = threadIdx.x;
    const float* yr = y   + (size_t)row * D_;
    const float* rr = res + (size_t)row * D_;

    float t[4];
    float sum = 0.f, sumsq = 0.f;
    #pragma unroll
    for (int i = 0; i < 4; i++) {
        int c = tid + 256 * i;
        t[i] = yr[c] + rr[c];
        sum += t[i]; sumsq += t[i] * t[i];
    }
    #pragma unroll
    for (int off = 32; off >= 1; off >>= 1) {
        sum   += __shfl_xor(sum,   off, 64);
        sumsq += __shfl_xor(sumsq, off, 64);
    }
    __shared__ float rs_[4], rq_[4];
    int w = tid >> 6, lane = tid & 63;
    if (lane == 0) { rs_[w] = sum; rq_[w] = sumsq; }
    __syncthreads();
    float tot  = rs_[0] + rs_[1] + rs_[2] + rs_[3];
    float totq = rq_[0] + rq_[1] + rq_[2] + rq_[3];
    float mu   = tot  * (1.f / D_);
    float var  = totq * (1.f / D_) - mu * mu;
    float rstd = rsqrtf(var + 1e-5f);

    float* orow = out + (size_t)row * D_;
    #pragma unroll
    for (int i = 0; i < 4; i++) {
        int c = tid + 256 * i;
        float val = (t[i] - mu) * rstd * g[c] + beta[c];
        orow[c] = val;
        if (outB) outB[(size_t)row * D_ + c] = f2b(val);
    }
}

// ---------------------------------------------------------------------------
extern "C" void kernel_launch(void* const* d_in, const int* in_sizes, int n_in,
                              void* d_out, int out_size, void* d_ws, size_t ws_size,
                              hipStream_t stream)
{
    const float* x   = (const float*)d_in[0];
    const float* Wq  = (const float*)d_in[2];
    const float* bq  = (const float*)d_in[3];
    const float* Wk  = (const float*)d_in[4];
    const float* bk  = (const float*)d_in[5];
    const float* Wv  = (const float*)d_in[6];
    const float* bv  = (const float*)d_in[7];
    const float* Wo  = (const float*)d_in[8];
    const float* bo  = (const float*)d_in[9];
    const float* phase_bias = (const float*)d_in[10];
    const float* freqs = (const float*)d_in[11];
    const float* W1  = (const float*)d_in[12];
    const float* b1  = (const float*)d_in[13];
    const float* W2  = (const float*)d_in[14];
    const float* b2  = (const float*)d_in[15];
    const float* g1  = (const float*)d_in[16];
    const float* be1 = (const float*)d_in[17];
    const float* g2  = (const float*)d_in[18];
    const float* be2 = (const float*)d_in[19];
    float* out = (float*)d_out;

    char* base = (char*)d_ws;
    const size_t MiB = 1024 * 1024;
    unsigned short* WqkvT = (unsigned short*)(base);             // 6 MiB [3072][1024]
    unsigned short* WoT   = (unsigned short*)(base + 6  * MiB);  // 2
    unsigned short* W1T   = (unsigned short*)(base + 8  * MiB);  // 8
    unsigned short* W2T   = (unsigned short*)(base + 16 * MiB);  // 8
    float*          bqkv  = (float*)(base + 24 * MiB);           // 12 KB
    unsigned short* xb    = (unsigned short*)(base + 25 * MiB);  // 8  [-> aob]
    float*          qkvf  = (float*)(base + 33 * MiB);           // 48 [-> hb]
    unsigned short* qpb   = (unsigned short*)(base + 81 * MiB);  // 16 [-> pf -> y2]
    unsigned short* kpb   = (unsigned short*)(base + 97 * MiB);  // 16 [-> x1]
    unsigned short* vtb   = (unsigned short*)(base + 113 * MiB); // 8  [-> x1b]
    unsigned short* aob   = (unsigned short*)(base + 25 * MiB);
    unsigned short* hb    = (unsigned short*)(base + 33 * MiB);
    float*          pf    = (float*)(base + 81 * MiB);
    float*          y2    = (float*)(base + 81 * MiB);
    float*          x1    = (float*)(base + 97 * MiB);
    unsigned short* x1b   = (unsigned short*)(base + 113 * MiB);

    dim3 blk(256);

    // prep
    conv_bf16_kernel<<<dim3(M_ * D_ / 256), blk, 0, stream>>>(x, xb);
    wtrans_kernel<<<dim3(32, 32), blk, 0, stream>>>(Wq, WqkvT, D_, D_);
    wtrans_kernel<<<dim3(32, 32), blk, 0, stream>>>(Wk, WqkvT + (size_t)1024 * 1024, D_, D_);
    wtrans_kernel<<<dim3(32, 32), blk, 0, stream>>>(Wv, WqkvT + (size_t)2048 * 1024, D_, D_);
    wtrans_kernel<<<dim3(32, 32), blk, 0, stream>>>(Wo, WoT, D_, D_);
    wtrans_kernel<<<dim3(DFF_ / 32, D_ / 32), blk, 0, stream>>>(W1, W1T, D_, DFF_);
    wtrans_kernel<<<dim3(D_ / 32, DFF_ / 32), blk, 0, stream>>>(W2, W2T, DFF_, D_);
    bcat_kernel<<<dim3(12), blk, 0, stream>>>(bq, bk, bv, bqkv);

    // fused QKV projection: (4096 x 1024) @ (1024 x 3072)
    gemm_bf16_kernel<<<dim3(3072 / 128, M_ / 128), blk, 0, stream>>>(
        xb, WqkvT, bqkv, qkvf, nullptr, M_, D_, 3072, 0);

    // PoPE + V transpose
    pope_kernel<<<dim3(B_ * H_ * S_ * HD_ / 256), blk, 0, stream>>>(qkvf, phase_bias, freqs, qpb, kpb);
    vtrans_kernel<<<dim3(S_ / 64, B_ * H_), blk, 0, stream>>>(qkvf, vtb);

    // Flash attention
    attn_mfma_kernel<<<dim3(S_ / 64, B_ * H_), blk, 0, stream>>>(qpb, kpb, vtb, aob);

    // Output projection + LN1
    gemm_bf16_kernel<<<dim3(D_ / 128, M_ / 128), blk, 0, stream>>>(
        aob, WoT, bo, pf, nullptr, M_, D_, D_, 0);
    ln_kernel<<<dim3(M_), blk, 0, stream>>>(pf, x, g1, be1, x1, x1b);

    // FFN
    gemm_bf16_kernel<<<dim3(DFF_ / 128, M_ / 128), blk, 0, stream>>>(
        x1b, W1T, b1, nullptr, hb, M_, D_, DFF_, 1);
    gemm_bf16_kernel<<<dim3(D_ / 128, M_ / 128), blk, 0, stream>>>(
        hb, W2T, b2, y2, nullptr, M_, DFF_, D_, 0);
    ln_kernel<<<dim3(M_), blk, 0, stream>>>(y2, x1, g2, be2, out, nullptr);
}